// Round 11
// baseline (4756.686 us; speedup 1.0000x reference)
//
#include <hip/hip_runtime.h>
#include <hip/hip_bf16.h>

#define B 32
#define S 512
#define H 1024
#define G 4096          // 4*H
#define NBLK 256
#define HSLOT 65536     // shorts per h slot (2 dirs x B x H)

typedef __attribute__((ext_vector_type(8))) short bf16x8;
typedef __attribute__((ext_vector_type(8))) unsigned short u16x8;
typedef __attribute__((ext_vector_type(4))) float f32x4;

__device__ __forceinline__ unsigned short f2bf(float v) {
    __hip_bfloat16 b = __float2bfloat16(v);
    return *reinterpret_cast<unsigned short*>(&b);
}
__device__ __forceinline__ float bf2f(unsigned short u) {
    union { float f; unsigned int i; } v; v.i = ((unsigned int)u) << 16; return v.f;
}
#define MFMA(a, b, c) __builtin_amdgcn_mfma_f32_16x16x32_bf16(a, b, c, 0, 0, 0)
#define ALOAD(p)    __hip_atomic_load((p),  __ATOMIC_RELAXED, __HIP_MEMORY_SCOPE_AGENT)
#define ASTORE(p,v) __hip_atomic_store((p), (v), __ATOMIC_RELAXED, __HIP_MEMORY_SCOPE_AGENT)

// =====================================================================
// prep_weights: fragment-ordered bf16 weights for one matrix pair (fw,bw).
// chunk idx = ((blk*4 + w)*16 + f)*64 + lane, 8 bf16/chunk; 1,048,576 chunks.
// =====================================================================
__global__ __launch_bounds__(256)
void prep_weights(const float* __restrict__ fw, const float* __restrict__ bw,
                  unsigned short* __restrict__ dst)
{
    size_t idx = (size_t)blockIdx.x * 256 + threadIdx.x;
    int lane = idx & 63;
    int f    = (idx >> 6) & 15;
    int w    = (idx >> 10) & 3;
    int blk  = (int)(idx >> 12);
    int dir  = blk >> 7, jg = blk & 127;
    int ks = f >> 1, ct = f & 1;

    int c  = ct * 16 + (lane & 15);
    int g  = (c >> 3) * H + jg * 8 + (c & 7);
    int kk = w * 256 + ks * 32 + ((lane >> 4) * 8);

    const float* src = dir ? bw : fw;
    u16x8 o;
#pragma unroll
    for (int i = 0; i < 8; ++i)
        o[i] = f2bf(src[(size_t)(kk + i) * G + g]);
    *(u16x8*)&dst[idx * 8] = o;
}

__global__ __launch_bounds__(256)
void prep_x(const float* __restrict__ x, unsigned short* __restrict__ xbf)
{
    size_t i8 = ((size_t)blockIdx.x * 256 + threadIdx.x) * 8;
    float4 v0 = *(const float4*)&x[i8];
    float4 v1 = *(const float4*)&x[i8 + 4];
    u16x8 o;
    o[0] = f2bf(v0.x); o[1] = f2bf(v0.y); o[2] = f2bf(v0.z); o[3] = f2bf(v0.w);
    o[4] = f2bf(v1.x); o[5] = f2bf(v1.y); o[6] = f2bf(v1.z); o[7] = f2bf(v1.w);
    *(u16x8*)&xbf[i8] = o;
}

// =====================================================================
// lstm_persist: one cooperative kernel, all 512 steps.
// 256 blocks x 512 threads. Block (dir,jg) owns 32 gate-cols.
// Barrier: ONE-HOP per-K-slice subset sync. Block publishes a single flag
// (contiguous dword flags[dir*128+jg]) when all 4 gate waves' h stores are
// vmcnt(0)-ack'd (LDS gcnt, 4th arrival stores). Consumer U-wave w polls
// ONLY its 32 producers (jg in [w*32,(w+1)*32)) -> 32 contiguous dwords =
// 2 cache lines, coalesced to ~2 LLC requests per poll iteration.
// Datapath (R9/R10-proven): h history buffer (fresh slot per step, regular
// pipelined bf16x8 loads); U frags in LDS; W-waves free-run x@W lookahead
// into an 8-slot LDS ring paced by gcnt.
// =====================================================================
__global__ __launch_bounds__(512, 1)
void lstm_persist(const unsigned short* __restrict__ wbufU,
                  const unsigned short* __restrict__ wbufW,
                  const unsigned short* __restrict__ xbf,
                  unsigned short* __restrict__ hhist,  // 513 slots x HSLOT
                  unsigned int* __restrict__ flags,    // 2 x 128 contiguous dwords
                  const float* __restrict__ pad,
                  const float* __restrict__ bfw, const float* __restrict__ bbw,
                  float* __restrict__ dout)
{
    const int blk = blockIdx.x;
    const int dir = blk >> 7;
    const int jg  = blk & 127;
    const int j0  = jg * 8;
    const int tid = threadIdx.x;
    const int wave = tid >> 6;
    const int lane = tid & 63;

    __shared__ short Uw[32768];                  // 64 KB U frags (wave-local regions)
    __shared__ float red[4][2][16][33];          // U partials
    __shared__ unsigned short ring[8][32][36];   // xz lookahead (bf16, bias folded)
    __shared__ unsigned rcnt;                    // red arrivals (monotone, 4/step)
    __shared__ unsigned gcnt;                    // gate publishes (monotone, 4/step)
    __shared__ int ring_ready[8];                // slot generation = fs+1

    if (tid == 0) { rcnt = 0; gcnt = 0; }
    if (tid < 8) ring_ready[tid] = 0;
    __syncthreads();   // the only block-wide barrier (init)

    const int arow  = lane & 15;
    const int akoff = (lane >> 4) * 8;
    const int drow  = (lane >> 4) * 4;
    const int dcol  = lane & 15;
    const float* bsrc = dir ? bbw : bfw;
    const float wb0 = bsrc[(dcol >> 3) * H + j0 + (dcol & 7)];
    const float wb1 = bsrc[(((16 + dcol) >> 3)) * H + j0 + ((16 + dcol) & 7)];

    if (wave < 4) {
        // ---- load this wave's U region into LDS (16 KB, wave-local) ----
        {
            const unsigned short* src = wbufU + (((size_t)blk * 4 + wave) * 16) * 512 + lane * 8;
#pragma unroll
            for (int f = 0; f < 16; ++f)
                *(u16x8*)&Uw[((wave * 16 + f) * 64 + lane) * 8] = *(const u16x8*)(src + f * 512);
        }

        float hst = 0.f, cst = 0.f;
        const int gb  = (tid >> 3) & 31;
        const int gj  = tid & 7;
        const int gbt = gb >> 4, grow = gb & 15;
        const f32x4 zero4 = {0.f, 0.f, 0.f, 0.f};
        const unsigned* fb = flags + (size_t)dir * 128 + wave * 32;

        for (int t = 0; t < S; ++t) {
            const int s = dir ? (S - 1 - t) : t;
            float pv = pad[gb * S + s];      // early issue, hidden under poll

            // ---- one-hop subset wait: this wave's 32 producers done t-1 ----
            if (t) {
                bool ok;
                do {
                    unsigned v = (lane < 32) ? ALOAD(&fb[lane]) : 0xffffffffu;
                    ok = __all(v >= (unsigned)t);
                } while (!ok);
                asm volatile("" ::: "memory");
            }

            // ---- U phase: h(t-1) @ U, K-slice wave*256, pipelined loads ----
            f32x4 u00 = zero4, u01 = zero4, u10 = zero4, u11 = zero4;
            const unsigned short* hb = hhist + (size_t)t * HSLOT
                                     + ((size_t)(dir * B) + arow) * H + wave * 256 + akoff;
#pragma unroll
            for (int ks = 0; ks < 8; ++ks) {
                bf16x8 a0 = *(const bf16x8*)(hb + ks * 32);
                bf16x8 a1 = *(const bf16x8*)(hb + 16 * H + ks * 32);
                bf16x8 b0 = *(const bf16x8*)&Uw[((wave * 16 + ks * 2 + 0) * 64 + lane) * 8];
                bf16x8 b1 = *(const bf16x8*)&Uw[((wave * 16 + ks * 2 + 1) * 64 + lane) * 8];
                u00 = MFMA(a0, b0, u00); u01 = MFMA(a0, b1, u01);
                u10 = MFMA(a1, b0, u10); u11 = MFMA(a1, b1, u11);
            }
#pragma unroll
            for (int r = 0; r < 4; ++r) {
                red[wave][0][drow + r][dcol]      = u00[r];
                red[wave][0][drow + r][16 + dcol] = u01[r];
                red[wave][1][drow + r][dcol]      = u10[r];
                red[wave][1][drow + r][16 + dcol] = u11[r];
            }
            asm volatile("s_waitcnt lgkmcnt(0)" ::: "memory");
            if (lane == 0) atomicAdd(&rcnt, 1u);
            {
                const unsigned need = 4u * (unsigned)(t + 1);
                while (*(volatile unsigned*)&rcnt < need) {}
                asm volatile("" ::: "memory");
            }

            // ---- ring slot t (normally ready 4+ steps ago) ----
            while (*(volatile int*)&ring_ready[t & 7] < t + 1) {}
            asm volatile("" ::: "memory");

            // ---- gate ----
            float z[4];
#pragma unroll
            for (int q = 0; q < 4; ++q) {
                const int c = q * 8 + gj;
                float zz = bf2f(ring[t & 7][gb][c]);
#pragma unroll
                for (int w = 0; w < 4; ++w) zz += red[w][gbt][grow][c];
                z[q] = zz;
            }
            float ig = 1.f / (1.f + expf(-z[0]));
            float fg = 1.f / (1.f + expf(-z[1]));
            float gg = tanhf(z[2]);
            float og = 1.f / (1.f + expf(-z[3]));

            float m  = 1.f - pv;
            float cn = fg * cst + ig * gg;
            float hn = og * tanhf(cn);
            float h2 = fmaf(m, hn - hst, hst);
            float c2 = fmaf(m, cn - cst, cst);
            hst = h2; cst = c2;

            // ---- publish h(t) -> hhist[t+1] (8B packed agent stores) ----
            unsigned u = (unsigned)f2bf(h2);
            const int gl = lane & ~3;
            unsigned v0 = (unsigned)__shfl((int)u, gl + 0);
            unsigned v1 = (unsigned)__shfl((int)u, gl + 1);
            unsigned v2 = (unsigned)__shfl((int)u, gl + 2);
            unsigned v3 = (unsigned)__shfl((int)u, gl + 3);
            if ((lane & 3) == 0) {
                unsigned long long pk = (unsigned long long)(v0 & 0xffffu)
                                      | ((unsigned long long)(v1 & 0xffffu) << 16)
                                      | ((unsigned long long)(v2 & 0xffffu) << 32)
                                      | ((unsigned long long)(v3 & 0xffffu) << 48);
                unsigned long long* hp = (unsigned long long*)
                    (hhist + (size_t)(t + 1) * HSLOT
                           + ((size_t)(dir * B) + gb) * H + j0 + gj);
                ASTORE(hp, pk);
            }
            // per-wave ack of own h stores, then 4th arrival publishes flag
            asm volatile("s_waitcnt vmcnt(0)" ::: "memory");
            if (lane == 0) {
                unsigned old = atomicAdd(&gcnt, 1u);
                if (old == 4u * (unsigned)t + 3u)
                    ASTORE(&flags[(size_t)dir * 128 + jg], (unsigned)(t + 1));
            }

            // ---- dout (off the publication path) ----
            dout[((size_t)gb * S + s) * (2 * H) + dir * H + j0 + gj] = h2;
            if (t == S - 1) {
                size_t base = (size_t)B * S * 2 * H;
                dout[base + dir * 2 * B * H + gb * H + j0 + gj] = h2;
                dout[base + dir * 2 * B * H + B * H + gb * H + j0 + gj] = c2;
            }
        }
    } else {
        // ---- W waves: free-running xz producer, fs = wave-4, +4 ----
        const f32x4 zero4 = {0.f, 0.f, 0.f, 0.f};
        for (int fs = wave - 4; fs < S; fs += 4) {
            if (fs >= 8) {   // wait until gate consumed slot (step fs-8 done)
                const unsigned need = 4u * (unsigned)(fs - 7);
                while (*(volatile unsigned*)&gcnt < need)
                    __builtin_amdgcn_s_sleep(2);   // coarse: >=4-step slack
                asm volatile("" ::: "memory");
            }
            const int s2 = dir ? (S - 1 - fs) : fs;
            f32x4 a00 = zero4, a01 = zero4, a10 = zero4, a11 = zero4;
            for (int sl = 0; sl < 4; ++sl) {
                const unsigned short* wbase =
                    wbufW + (((size_t)blk * 4 + sl) * 16) * 512 + lane * 8;
                bf16x8 wf[16];
#pragma unroll
                for (int f = 0; f < 16; ++f) wf[f] = *(const bf16x8*)(wbase + f * 512);
                const unsigned short* A0 =
                    xbf + ((size_t)arow * S + s2) * H + sl * 256 + akoff;
#pragma unroll
                for (int ks = 0; ks < 8; ++ks) {
                    bf16x8 x0 = *(const bf16x8*)(A0 + ks * 32);
                    bf16x8 x1 = *(const bf16x8*)(A0 + (size_t)16 * S * H + ks * 32);
                    a00 = MFMA(x0, wf[ks*2+0], a00); a01 = MFMA(x0, wf[ks*2+1], a01);
                    a10 = MFMA(x1, wf[ks*2+0], a10); a11 = MFMA(x1, wf[ks*2+1], a11);
                }
            }
            const int slot = fs & 7;
#pragma unroll
            for (int r = 0; r < 4; ++r) {
                ring[slot][drow + r][dcol]           = f2bf(a00[r] + wb0);
                ring[slot][drow + r][16 + dcol]      = f2bf(a01[r] + wb1);
                ring[slot][16 + drow + r][dcol]      = f2bf(a10[r] + wb0);
                ring[slot][16 + drow + r][16 + dcol] = f2bf(a11[r] + wb1);
            }
            asm volatile("s_waitcnt lgkmcnt(0)" ::: "memory");
            if (lane == 0) *(volatile int*)&ring_ready[slot] = fs + 1;
        }
    }
}

// =====================================================================
// Host side
// =====================================================================
extern "C" void kernel_launch(void* const* d_in, const int* in_sizes, int n_in,
                              void* d_out, int out_size, void* d_ws, size_t ws_size,
                              hipStream_t stream)
{
    const float* x   = (const float*)d_in[0];
    const float* pad = (const float*)d_in[1];
    const float* Wfw = (const float*)d_in[2];
    const float* Ufw = (const float*)d_in[3];
    const float* bfw = (const float*)d_in[4];
    const float* Wbw = (const float*)d_in[5];
    const float* Ubw = (const float*)d_in[6];
    const float* bbw = (const float*)d_in[7];
    float* out = (float*)d_out;

    char* w = (char*)d_ws;
    unsigned short* wbufW = (unsigned short*)w;                     // 16.8 MB
    unsigned short* wbufU = wbufW + (size_t)1048576 * 8;            // 16.8 MB
    unsigned short* xbf   = wbufU + (size_t)1048576 * 8;            // 33.6 MB
    unsigned short* hhist = xbf + (size_t)B * S * H;                // 513 x 128 KB
    unsigned int*   flags = (unsigned int*)(hhist + (size_t)(S + 1) * HSLOT); // 1 KB

    // zero h slot 0 + flags (deterministic per call)
    hipMemsetAsync(hhist, 0, (size_t)HSLOT * sizeof(unsigned short), stream);
    hipMemsetAsync(flags, 0, 256 * sizeof(unsigned int), stream);

    prep_x<<<8192, 256, 0, stream>>>(x, xbf);
    prep_weights<<<4096, 256, 0, stream>>>(Wfw, Wbw, wbufW);
    prep_weights<<<4096, 256, 0, stream>>>(Ufw, Ubw, wbufU);

    void* args[] = { (void*)&wbufU, (void*)&wbufW, (void*)&xbf, (void*)&hhist,
                     (void*)&flags, (void*)&pad,
                     (void*)&bfw, (void*)&bbw, (void*)&out };
    hipLaunchCooperativeKernel((void*)lstm_persist, dim3(NBLK), dim3(512),
                               args, 0, stream);
}

// Round 12
// 3591.196 us; speedup vs baseline: 1.3245x; 1.3245x over previous
//
#include <hip/hip_runtime.h>
#include <hip/hip_bf16.h>

#define B 32
#define S 512
#define H 1024
#define G 4096          // 4*H
#define NBLK 256
#define HSLOT 65536     // shorts per h slot (2 dirs x B x H)

typedef __attribute__((ext_vector_type(8))) short bf16x8;
typedef __attribute__((ext_vector_type(8))) unsigned short u16x8;
typedef __attribute__((ext_vector_type(4))) float f32x4;

__device__ __forceinline__ unsigned short f2bf(float v) {
    __hip_bfloat16 b = __float2bfloat16(v);
    return *reinterpret_cast<unsigned short*>(&b);
}
__device__ __forceinline__ float bf2f(unsigned short u) {
    union { float f; unsigned int i; } v; v.i = ((unsigned int)u) << 16; return v.f;
}
#define MFMA(a, b, c) __builtin_amdgcn_mfma_f32_16x16x32_bf16(a, b, c, 0, 0, 0)
#define ALOAD(p)    __hip_atomic_load((p),  __ATOMIC_RELAXED, __HIP_MEMORY_SCOPE_AGENT)
#define ASTORE(p,v) __hip_atomic_store((p), (v), __ATOMIC_RELAXED, __HIP_MEMORY_SCOPE_AGENT)

// =====================================================================
// prep_weights: fragment-ordered bf16 weights for one matrix pair (fw,bw).
// chunk idx = ((blk*4 + w)*16 + f)*64 + lane, 8 bf16/chunk; 1,048,576 chunks.
// =====================================================================
__global__ __launch_bounds__(256)
void prep_weights(const float* __restrict__ fw, const float* __restrict__ bw,
                  unsigned short* __restrict__ dst)
{
    size_t idx = (size_t)blockIdx.x * 256 + threadIdx.x;
    int lane = idx & 63;
    int f    = (idx >> 6) & 15;
    int w    = (idx >> 10) & 3;
    int blk  = (int)(idx >> 12);
    int dir  = blk >> 7, jg = blk & 127;
    int ks = f >> 1, ct = f & 1;

    int c  = ct * 16 + (lane & 15);
    int g  = (c >> 3) * H + jg * 8 + (c & 7);
    int kk = w * 256 + ks * 32 + ((lane >> 4) * 8);

    const float* src = dir ? bw : fw;
    u16x8 o;
#pragma unroll
    for (int i = 0; i < 8; ++i)
        o[i] = f2bf(src[(size_t)(kk + i) * G + g]);
    *(u16x8*)&dst[idx * 8] = o;
}

__global__ __launch_bounds__(256)
void prep_x(const float* __restrict__ x, unsigned short* __restrict__ xbf)
{
    size_t i8 = ((size_t)blockIdx.x * 256 + threadIdx.x) * 8;
    float4 v0 = *(const float4*)&x[i8];
    float4 v1 = *(const float4*)&x[i8 + 4];
    u16x8 o;
    o[0] = f2bf(v0.x); o[1] = f2bf(v0.y); o[2] = f2bf(v0.z); o[3] = f2bf(v0.w);
    o[4] = f2bf(v1.x); o[5] = f2bf(v1.y); o[6] = f2bf(v1.z); o[7] = f2bf(v1.w);
    *(u16x8*)&xbf[i8] = o;
}

// =====================================================================
// lstm_persist: one cooperative kernel, all 512 steps.
// 256 blocks x 512 threads. Block (dir,jg) owns 32 gate-cols.
// Barrier (R10 topology + dedicated sync wave): block publishes one flag
// on its private 64B line (plain store after vmcnt(0)-ack of h stores,
// 4th gate-wave arrival via LDS gcnt). In the two master blocks (jg==0),
// wave 7 does NOTHING but scan the 128 flags of its direction and
// plain-store gen[dir] — continuous, so detect latency is minimal and
// decoupled from the master's own compute. All blocks' wave0 polls the
// single-writer gen line; LDS token relays to waves 1-3.
// Priority: U/gate waves + sync wave setprio(1); W waves stay 0.
// Datapath (R9/R10-proven): h history buffer (fresh 128 KB slot per step,
// regular pipelined bf16x8 loads -> L2-miss-fresh by construction);
// U frags in LDS; W-waves free-run x@W into 8-slot LDS ring paced by
// gcnt (stride 3 in master blocks since wave 7 is the sync wave).
// =====================================================================
__global__ __launch_bounds__(512, 1)
void lstm_persist(const unsigned short* __restrict__ wbufU,
                  const unsigned short* __restrict__ wbufW,
                  const unsigned short* __restrict__ xbf,
                  unsigned short* __restrict__ hhist,  // 513 slots x HSLOT
                  unsigned int* __restrict__ flags,    // 256 x 16 (64B stride)
                  unsigned int* __restrict__ gen,      // [dir*32]
                  const float* __restrict__ pad,
                  const float* __restrict__ bfw, const float* __restrict__ bbw,
                  float* __restrict__ dout)
{
    const int blk = blockIdx.x;
    const int dir = blk >> 7;
    const int jg  = blk & 127;
    const int j0  = jg * 8;
    const int tid = threadIdx.x;
    const int wave = tid >> 6;
    const int lane = tid & 63;
    const bool is_master = (jg == 0);   // blk 0 (dir0) and blk 128 (dir1)

    __shared__ short Uw[32768];                  // 64 KB U frags (wave-local regions)
    __shared__ float red[4][2][16][33];          // U partials
    __shared__ unsigned short ring[8][32][36];   // xz lookahead (bf16, bias folded)
    __shared__ unsigned rcnt;                    // red arrivals (monotone, 4/step)
    __shared__ unsigned gcnt;                    // gate publishes (monotone, 4/step)
    __shared__ unsigned tok;                     // gen-poll relay

    __shared__ int ring_ready[8];                // slot generation = fs+1

    if (tid == 0) { rcnt = 0; gcnt = 0; tok = 0; }
    if (tid < 8) ring_ready[tid] = 0;
    __syncthreads();   // the only block-wide barrier (init)

    const int arow  = lane & 15;
    const int akoff = (lane >> 4) * 8;
    const int drow  = (lane >> 4) * 4;
    const int dcol  = lane & 15;
    const float* bsrc = dir ? bbw : bfw;
    const float wb0 = bsrc[(dcol >> 3) * H + j0 + (dcol & 7)];
    const float wb1 = bsrc[(((16 + dcol) >> 3)) * H + j0 + ((16 + dcol) & 7)];

    if (wave < 4) {
        __builtin_amdgcn_s_setprio(1);   // favor the serial chain
        // ---- load this wave's U region into LDS (16 KB, wave-local) ----
        {
            const unsigned short* src = wbufU + (((size_t)blk * 4 + wave) * 16) * 512 + lane * 8;
#pragma unroll
            for (int f = 0; f < 16; ++f)
                *(u16x8*)&Uw[((wave * 16 + f) * 64 + lane) * 8] = *(const u16x8*)(src + f * 512);
        }

        float hst = 0.f, cst = 0.f;
        const int gb  = (tid >> 3) & 31;
        const int gj  = tid & 7;
        const int gbt = gb >> 4, grow = gb & 15;
        const f32x4 zero4 = {0.f, 0.f, 0.f, 0.f};

        for (int t = 0; t < S; ++t) {
            const int s = dir ? (S - 1 - t) : t;
            float pv = pad[gb * S + s];      // early issue, hidden under poll

            // ---- wait for step t-1 publications of this direction ----
            if (t) {
                if (wave == 0) {
                    while (ALOAD(&gen[dir * 32]) < (unsigned)t)
                        __builtin_amdgcn_s_sleep(1);
                    asm volatile("" ::: "memory");
                    if (lane == 0) *(volatile unsigned*)&tok = (unsigned)t;
                } else {
                    while (*(volatile unsigned*)&tok < (unsigned)t) {}
                }
                asm volatile("" ::: "memory");
            }

            // ---- U phase: h(t-1) @ U, K-slice wave*256, pipelined loads ----
            f32x4 u00 = zero4, u01 = zero4, u10 = zero4, u11 = zero4;
            const unsigned short* hb = hhist + (size_t)t * HSLOT
                                     + ((size_t)(dir * B) + arow) * H + wave * 256 + akoff;
#pragma unroll
            for (int ks = 0; ks < 8; ++ks) {
                bf16x8 a0 = *(const bf16x8*)(hb + ks * 32);
                bf16x8 a1 = *(const bf16x8*)(hb + 16 * H + ks * 32);
                bf16x8 b0 = *(const bf16x8*)&Uw[((wave * 16 + ks * 2 + 0) * 64 + lane) * 8];
                bf16x8 b1 = *(const bf16x8*)&Uw[((wave * 16 + ks * 2 + 1) * 64 + lane) * 8];
                u00 = MFMA(a0, b0, u00); u01 = MFMA(a0, b1, u01);
                u10 = MFMA(a1, b0, u10); u11 = MFMA(a1, b1, u11);
            }
#pragma unroll
            for (int r = 0; r < 4; ++r) {
                red[wave][0][drow + r][dcol]      = u00[r];
                red[wave][0][drow + r][16 + dcol] = u01[r];
                red[wave][1][drow + r][dcol]      = u10[r];
                red[wave][1][drow + r][16 + dcol] = u11[r];
            }
            asm volatile("s_waitcnt lgkmcnt(0)" ::: "memory");
            if (lane == 0) atomicAdd(&rcnt, 1u);
            {
                const unsigned need = 4u * (unsigned)(t + 1);
                while (*(volatile unsigned*)&rcnt < need) {}
                asm volatile("" ::: "memory");
            }

            // ---- ring slot t (normally ready 4+ steps ago) ----
            while (*(volatile int*)&ring_ready[t & 7] < t + 1) {}
            asm volatile("" ::: "memory");

            // ---- gate ----
            float z[4];
#pragma unroll
            for (int q = 0; q < 4; ++q) {
                const int c = q * 8 + gj;
                float zz = bf2f(ring[t & 7][gb][c]);
#pragma unroll
                for (int w = 0; w < 4; ++w) zz += red[w][gbt][grow][c];
                z[q] = zz;
            }
            float ig = 1.f / (1.f + expf(-z[0]));
            float fg = 1.f / (1.f + expf(-z[1]));
            float gg = tanhf(z[2]);
            float og = 1.f / (1.f + expf(-z[3]));

            float m  = 1.f - pv;
            float cn = fg * cst + ig * gg;
            float hn = og * tanhf(cn);
            float h2 = fmaf(m, hn - hst, hst);
            float c2 = fmaf(m, cn - cst, cst);
            hst = h2; cst = c2;

            // ---- publish h(t) -> hhist[t+1] (8B packed agent stores) ----
            unsigned u = (unsigned)f2bf(h2);
            const int gl = lane & ~3;
            unsigned v0 = (unsigned)__shfl((int)u, gl + 0);
            unsigned v1 = (unsigned)__shfl((int)u, gl + 1);
            unsigned v2 = (unsigned)__shfl((int)u, gl + 2);
            unsigned v3 = (unsigned)__shfl((int)u, gl + 3);
            if ((lane & 3) == 0) {
                unsigned long long pk = (unsigned long long)(v0 & 0xffffu)
                                      | ((unsigned long long)(v1 & 0xffffu) << 16)
                                      | ((unsigned long long)(v2 & 0xffffu) << 32)
                                      | ((unsigned long long)(v3 & 0xffffu) << 48);
                unsigned long long* hp = (unsigned long long*)
                    (hhist + (size_t)(t + 1) * HSLOT
                           + ((size_t)(dir * B) + gb) * H + j0 + gj);
                ASTORE(hp, pk);
            }
            // per-wave ack of own h stores, then 4th arrival publishes flag
            asm volatile("s_waitcnt vmcnt(0)" ::: "memory");
            if (lane == 0) {
                unsigned old = atomicAdd(&gcnt, 1u);
                if (old == 4u * (unsigned)t + 3u)
                    ASTORE(&flags[(size_t)blk * 16], (unsigned)(t + 1));
            }

            // ---- dout (off the publication path) ----
            dout[((size_t)gb * S + s) * (2 * H) + dir * H + j0 + gj] = h2;
            if (t == S - 1) {
                size_t base = (size_t)B * S * 2 * H;
                dout[base + dir * 2 * B * H + gb * H + j0 + gj] = h2;
                dout[base + dir * 2 * B * H + B * H + gb * H + j0 + gj] = c2;
            }
        }
    } else if (is_master && wave == 7) {
        // ---- dedicated sync wave: continuous scan -> gen broadcast ----
        __builtin_amdgcn_s_setprio(1);
        const unsigned* fb = flags + (size_t)dir * 128 * 16;
        for (int t = 1; t < S; ++t) {
            bool allok;
            do {
                unsigned v0 = ALOAD(&fb[(lane * 2 + 0) * 16]);
                unsigned v1 = ALOAD(&fb[(lane * 2 + 1) * 16]);
                allok = __all(v0 >= (unsigned)t && v1 >= (unsigned)t);
            } while (!allok);
            if (lane == 0) ASTORE(&gen[dir * 32], (unsigned)t);
        }
    } else {
        // ---- W waves: free-running xz producer ----
        // masters: waves 4-6, stride 3 (wave 7 is the sync wave);
        // others:  waves 4-7, stride 4. Both cover every fs.
        const int stride = is_master ? 3 : 4;
        const f32x4 zero4 = {0.f, 0.f, 0.f, 0.f};
        for (int fs = wave - 4; fs < S; fs += stride) {
            if (fs >= 8) {   // wait until gate consumed slot (step fs-8 done)
                const unsigned need = 4u * (unsigned)(fs - 7);
                while (*(volatile unsigned*)&gcnt < need)
                    __builtin_amdgcn_s_sleep(2);   // coarse: >=4-step slack
                asm volatile("" ::: "memory");
            }
            const int s2 = dir ? (S - 1 - fs) : fs;
            f32x4 a00 = zero4, a01 = zero4, a10 = zero4, a11 = zero4;
            for (int sl = 0; sl < 4; ++sl) {
                const unsigned short* wbase =
                    wbufW + (((size_t)blk * 4 + sl) * 16) * 512 + lane * 8;
                bf16x8 wf[16];
#pragma unroll
                for (int f = 0; f < 16; ++f) wf[f] = *(const bf16x8*)(wbase + f * 512);
                const unsigned short* A0 =
                    xbf + ((size_t)arow * S + s2) * H + sl * 256 + akoff;
#pragma unroll
                for (int ks = 0; ks < 8; ++ks) {
                    bf16x8 x0 = *(const bf16x8*)(A0 + ks * 32);
                    bf16x8 x1 = *(const bf16x8*)(A0 + (size_t)16 * S * H + ks * 32);
                    a00 = MFMA(x0, wf[ks*2+0], a00); a01 = MFMA(x0, wf[ks*2+1], a01);
                    a10 = MFMA(x1, wf[ks*2+0], a10); a11 = MFMA(x1, wf[ks*2+1], a11);
                }
            }
            const int slot = fs & 7;
#pragma unroll
            for (int r = 0; r < 4; ++r) {
                ring[slot][drow + r][dcol]           = f2bf(a00[r] + wb0);
                ring[slot][drow + r][16 + dcol]      = f2bf(a01[r] + wb1);
                ring[slot][16 + drow + r][dcol]      = f2bf(a10[r] + wb0);
                ring[slot][16 + drow + r][16 + dcol] = f2bf(a11[r] + wb1);
            }
            asm volatile("s_waitcnt lgkmcnt(0)" ::: "memory");
            if (lane == 0) *(volatile int*)&ring_ready[slot] = fs + 1;
        }
    }
}

// =====================================================================
// Host side
// =====================================================================
extern "C" void kernel_launch(void* const* d_in, const int* in_sizes, int n_in,
                              void* d_out, int out_size, void* d_ws, size_t ws_size,
                              hipStream_t stream)
{
    const float* x   = (const float*)d_in[0];
    const float* pad = (const float*)d_in[1];
    const float* Wfw = (const float*)d_in[2];
    const float* Ufw = (const float*)d_in[3];
    const float* bfw = (const float*)d_in[4];
    const float* Wbw = (const float*)d_in[5];
    const float* Ubw = (const float*)d_in[6];
    const float* bbw = (const float*)d_in[7];
    float* out = (float*)d_out;

    char* w = (char*)d_ws;
    unsigned short* wbufW = (unsigned short*)w;                     // 16.8 MB
    unsigned short* wbufU = wbufW + (size_t)1048576 * 8;            // 16.8 MB
    unsigned short* xbf   = wbufU + (size_t)1048576 * 8;            // 33.6 MB
    unsigned short* hhist = xbf + (size_t)B * S * H;                // 513 x 128 KB
    unsigned int*   flags = (unsigned int*)(hhist + (size_t)(S + 1) * HSLOT); // 16 KB
    unsigned int*   gen   = flags + 256 * 16;                       // 64 uints

    // zero h slot 0, flags, gen (deterministic per call)
    hipMemsetAsync(hhist, 0, (size_t)HSLOT * sizeof(unsigned short), stream);
    hipMemsetAsync(flags, 0, (256 * 16 + 64) * sizeof(unsigned int), stream);

    prep_x<<<8192, 256, 0, stream>>>(x, xbf);
    prep_weights<<<4096, 256, 0, stream>>>(Wfw, Wbw, wbufW);
    prep_weights<<<4096, 256, 0, stream>>>(Ufw, Ubw, wbufU);

    void* args[] = { (void*)&wbufU, (void*)&wbufW, (void*)&xbf, (void*)&hhist,
                     (void*)&flags, (void*)&gen, (void*)&pad,
                     (void*)&bfw, (void*)&bbw, (void*)&out };
    hipLaunchCooperativeKernel((void*)lstm_persist, dim3(NBLK), dim3(512),
                               args, 0, stream);
}

// Round 13
// 3590.940 us; speedup vs baseline: 1.3246x; 1.0001x over previous
//
#include <hip/hip_runtime.h>
#include <hip/hip_bf16.h>

#define B 32
#define S 512
#define H 1024
#define G 4096          // 4*H
#define NBLK 256
#define HSLOT 65536     // shorts per h slot (2 dirs x B x H)

typedef __attribute__((ext_vector_type(8))) short bf16x8;
typedef __attribute__((ext_vector_type(8))) unsigned short u16x8;
typedef __attribute__((ext_vector_type(4))) float f32x4;

__device__ __forceinline__ unsigned short f2bf(float v) {
    __hip_bfloat16 b = __float2bfloat16(v);
    return *reinterpret_cast<unsigned short*>(&b);
}
__device__ __forceinline__ float bf2f(unsigned short u) {
    union { float f; unsigned int i; } v; v.i = ((unsigned int)u) << 16; return v.f;
}
#define MFMA(a, b, c) __builtin_amdgcn_mfma_f32_16x16x32_bf16(a, b, c, 0, 0, 0)
#define ALOAD(p)    __hip_atomic_load((p),  __ATOMIC_RELAXED, __HIP_MEMORY_SCOPE_AGENT)
#define ASTORE(p,v) __hip_atomic_store((p), (v), __ATOMIC_RELAXED, __HIP_MEMORY_SCOPE_AGENT)

// =====================================================================
// prep_weights: fragment-ordered bf16 weights for one matrix pair (fw,bw).
// chunk idx = ((blk*4 + w)*16 + f)*64 + lane, 8 bf16/chunk; 1,048,576 chunks.
// =====================================================================
__global__ __launch_bounds__(256)
void prep_weights(const float* __restrict__ fw, const float* __restrict__ bw,
                  unsigned short* __restrict__ dst)
{
    size_t idx = (size_t)blockIdx.x * 256 + threadIdx.x;
    int lane = idx & 63;
    int f    = (idx >> 6) & 15;
    int w    = (idx >> 10) & 3;
    int blk  = (int)(idx >> 12);
    int dir  = blk >> 7, jg = blk & 127;
    int ks = f >> 1, ct = f & 1;

    int c  = ct * 16 + (lane & 15);
    int g  = (c >> 3) * H + jg * 8 + (c & 7);
    int kk = w * 256 + ks * 32 + ((lane >> 4) * 8);

    const float* src = dir ? bw : fw;
    u16x8 o;
#pragma unroll
    for (int i = 0; i < 8; ++i)
        o[i] = f2bf(src[(size_t)(kk + i) * G + g]);
    *(u16x8*)&dst[idx * 8] = o;
}

__global__ __launch_bounds__(256)
void prep_x(const float* __restrict__ x, unsigned short* __restrict__ xbf)
{
    size_t i8 = ((size_t)blockIdx.x * 256 + threadIdx.x) * 8;
    float4 v0 = *(const float4*)&x[i8];
    float4 v1 = *(const float4*)&x[i8 + 4];
    u16x8 o;
    o[0] = f2bf(v0.x); o[1] = f2bf(v0.y); o[2] = f2bf(v0.z); o[3] = f2bf(v0.w);
    o[4] = f2bf(v1.x); o[5] = f2bf(v1.y); o[6] = f2bf(v1.z); o[7] = f2bf(v1.w);
    *(u16x8*)&xbf[i8] = o;
}

// =====================================================================
// lstm_persist: one cooperative kernel, all 512 steps.
// 256 blocks x 512 threads. Block (dir,jg) owns 32 gate-cols.
// Barrier (per-K-quarter, one hop, single-scanner/single-writer):
//  - producer: block stores flags[dir*128+jg] (contiguous dwords) when all
//    4 gate waves' h stores are vmcnt(0)-ack'd (LDS gcnt, 4th arrival).
//  - master block (jg==0): U-wave w scans ONLY quarter w (32 contiguous
//    flags = 2 lines) and publishes gen4[dir][w] (own 64B line, 1 writer).
//  - consumers: U-wave w of every other block polls gen4[dir][w] (1
//    coalesced read/iter). No relay hop; quarter skew overlaps with the
//    h-load/MFMA of earlier-ready quarters.
// Datapath (R9/R10-proven): h history buffer (fresh 128 KB slot per step,
// regular pipelined bf16x8 loads); U frags in LDS; W-waves (4/block
// everywhere) free-run x@W into 8-slot LDS ring paced by gcnt.
// =====================================================================
__global__ __launch_bounds__(512, 1)
void lstm_persist(const unsigned short* __restrict__ wbufU,
                  const unsigned short* __restrict__ wbufW,
                  const unsigned short* __restrict__ xbf,
                  unsigned short* __restrict__ hhist,  // 513 slots x HSLOT
                  unsigned int* __restrict__ flags,    // 2 x 128 contiguous dwords
                  unsigned int* __restrict__ gen4,     // [dir*4+w]*16 (64B lines)
                  const float* __restrict__ pad,
                  const float* __restrict__ bfw, const float* __restrict__ bbw,
                  float* __restrict__ dout)
{
    const int blk = blockIdx.x;
    const int dir = blk >> 7;
    const int jg  = blk & 127;
    const int j0  = jg * 8;
    const int tid = threadIdx.x;
    const int wave = tid >> 6;
    const int lane = tid & 63;
    const bool is_master = (jg == 0);   // blk 0 (dir0) and blk 128 (dir1)

    __shared__ short Uw[32768];                  // 64 KB U frags (wave-local regions)
    __shared__ float red[4][2][16][33];          // U partials
    __shared__ unsigned short ring[8][32][36];   // xz lookahead (bf16, bias folded)
    __shared__ unsigned rcnt;                    // red arrivals (monotone, 4/step)
    __shared__ unsigned gcnt;                    // gate publishes (monotone, 4/step)
    __shared__ int ring_ready[8];                // slot generation = fs+1

    if (tid == 0) { rcnt = 0; gcnt = 0; }
    if (tid < 8) ring_ready[tid] = 0;
    __syncthreads();   // the only block-wide barrier (init)

    const int arow  = lane & 15;
    const int akoff = (lane >> 4) * 8;
    const int drow  = (lane >> 4) * 4;
    const int dcol  = lane & 15;
    const float* bsrc = dir ? bbw : bfw;
    const float wb0 = bsrc[(dcol >> 3) * H + j0 + (dcol & 7)];
    const float wb1 = bsrc[(((16 + dcol) >> 3)) * H + j0 + ((16 + dcol) & 7)];

    if (wave < 4) {
        __builtin_amdgcn_s_setprio(1);   // favor the serial chain
        // ---- load this wave's U region into LDS (16 KB, wave-local) ----
        {
            const unsigned short* src = wbufU + (((size_t)blk * 4 + wave) * 16) * 512 + lane * 8;
#pragma unroll
            for (int f = 0; f < 16; ++f)
                *(u16x8*)&Uw[((wave * 16 + f) * 64 + lane) * 8] = *(const u16x8*)(src + f * 512);
        }

        float hst = 0.f, cst = 0.f;
        const int gb  = (tid >> 3) & 31;
        const int gj  = tid & 7;
        const int gbt = gb >> 4, grow = gb & 15;
        const f32x4 zero4 = {0.f, 0.f, 0.f, 0.f};
        const unsigned* fq = flags + (size_t)dir * 128 + wave * 32;  // this wave's quarter
        unsigned int* gline = gen4 + ((size_t)dir * 4 + wave) * 16;

        for (int t = 0; t < S; ++t) {
            const int s = dir ? (S - 1 - t) : t;
            float pv = pad[gb * S + s];      // early issue, hidden under poll

            // ---- wait for quarter `wave` of step t-1 ----
            if (t) {
                if (is_master) {
                    bool ok;
                    do {
                        unsigned v = ALOAD(&fq[lane & 31]);
                        ok = __all(v >= (unsigned)t);
                        if (!ok) __builtin_amdgcn_s_sleep(1);
                    } while (!ok);
                    if (lane == 0) ASTORE(gline, (unsigned)t);
                } else {
                    while (ALOAD(gline) < (unsigned)t)
                        __builtin_amdgcn_s_sleep(1);
                }
                asm volatile("" ::: "memory");
            }

            // ---- U phase: h(t-1) @ U, K-slice wave*256, pipelined loads ----
            f32x4 u00 = zero4, u01 = zero4, u10 = zero4, u11 = zero4;
            const unsigned short* hb = hhist + (size_t)t * HSLOT
                                     + ((size_t)(dir * B) + arow) * H + wave * 256 + akoff;
#pragma unroll
            for (int ks = 0; ks < 8; ++ks) {
                bf16x8 a0 = *(const bf16x8*)(hb + ks * 32);
                bf16x8 a1 = *(const bf16x8*)(hb + 16 * H + ks * 32);
                bf16x8 b0 = *(const bf16x8*)&Uw[((wave * 16 + ks * 2 + 0) * 64 + lane) * 8];
                bf16x8 b1 = *(const bf16x8*)&Uw[((wave * 16 + ks * 2 + 1) * 64 + lane) * 8];
                u00 = MFMA(a0, b0, u00); u01 = MFMA(a0, b1, u01);
                u10 = MFMA(a1, b0, u10); u11 = MFMA(a1, b1, u11);
            }
#pragma unroll
            for (int r = 0; r < 4; ++r) {
                red[wave][0][drow + r][dcol]      = u00[r];
                red[wave][0][drow + r][16 + dcol] = u01[r];
                red[wave][1][drow + r][dcol]      = u10[r];
                red[wave][1][drow + r][16 + dcol] = u11[r];
            }
            asm volatile("s_waitcnt lgkmcnt(0)" ::: "memory");
            if (lane == 0) atomicAdd(&rcnt, 1u);
            {
                const unsigned need = 4u * (unsigned)(t + 1);
                while (*(volatile unsigned*)&rcnt < need) {}
                asm volatile("" ::: "memory");
            }

            // ---- ring slot t (normally ready 4+ steps ago) ----
            while (*(volatile int*)&ring_ready[t & 7] < t + 1) {}
            asm volatile("" ::: "memory");

            // ---- gate ----
            float z[4];
#pragma unroll
            for (int q = 0; q < 4; ++q) {
                const int c = q * 8 + gj;
                float zz = bf2f(ring[t & 7][gb][c]);
#pragma unroll
                for (int w = 0; w < 4; ++w) zz += red[w][gbt][grow][c];
                z[q] = zz;
            }
            float ig = 1.f / (1.f + expf(-z[0]));
            float fg = 1.f / (1.f + expf(-z[1]));
            float gg = tanhf(z[2]);
            float og = 1.f / (1.f + expf(-z[3]));

            float m  = 1.f - pv;
            float cn = fg * cst + ig * gg;
            float hn = og * tanhf(cn);
            float h2 = fmaf(m, hn - hst, hst);
            float c2 = fmaf(m, cn - cst, cst);
            hst = h2; cst = c2;

            // ---- publish h(t) -> hhist[t+1] (8B packed agent stores) ----
            unsigned u = (unsigned)f2bf(h2);
            const int gl = lane & ~3;
            unsigned v0 = (unsigned)__shfl((int)u, gl + 0);
            unsigned v1 = (unsigned)__shfl((int)u, gl + 1);
            unsigned v2 = (unsigned)__shfl((int)u, gl + 2);
            unsigned v3 = (unsigned)__shfl((int)u, gl + 3);
            if ((lane & 3) == 0) {
                unsigned long long pk = (unsigned long long)(v0 & 0xffffu)
                                      | ((unsigned long long)(v1 & 0xffffu) << 16)
                                      | ((unsigned long long)(v2 & 0xffffu) << 32)
                                      | ((unsigned long long)(v3 & 0xffffu) << 48);
                unsigned long long* hp = (unsigned long long*)
                    (hhist + (size_t)(t + 1) * HSLOT
                           + ((size_t)(dir * B) + gb) * H + j0 + gj);
                ASTORE(hp, pk);
            }
            // per-wave ack of own h stores, then 4th arrival publishes flag
            asm volatile("s_waitcnt vmcnt(0)" ::: "memory");
            if (lane == 0) {
                unsigned old = atomicAdd(&gcnt, 1u);
                if (old == 4u * (unsigned)t + 3u)
                    ASTORE(&flags[(size_t)dir * 128 + jg], (unsigned)(t + 1));
            }

            // ---- dout (off the publication path) ----
            dout[((size_t)gb * S + s) * (2 * H) + dir * H + j0 + gj] = h2;
            if (t == S - 1) {
                size_t base = (size_t)B * S * 2 * H;
                dout[base + dir * 2 * B * H + gb * H + j0 + gj] = h2;
                dout[base + dir * 2 * B * H + B * H + gb * H + j0 + gj] = c2;
            }
        }
    } else {
        // ---- W waves: free-running xz producer, fs = wave-4, +4 ----
        const f32x4 zero4 = {0.f, 0.f, 0.f, 0.f};
        for (int fs = wave - 4; fs < S; fs += 4) {
            if (fs >= 8) {   // wait until gate consumed slot (step fs-8 done)
                const unsigned need = 4u * (unsigned)(fs - 7);
                while (*(volatile unsigned*)&gcnt < need)
                    __builtin_amdgcn_s_sleep(2);   // coarse: >=4-step slack
                asm volatile("" ::: "memory");
            }
            const int s2 = dir ? (S - 1 - fs) : fs;
            f32x4 a00 = zero4, a01 = zero4, a10 = zero4, a11 = zero4;
            for (int sl = 0; sl < 4; ++sl) {
                const unsigned short* wbase =
                    wbufW + (((size_t)blk * 4 + sl) * 16) * 512 + lane * 8;
                bf16x8 wf[16];
#pragma unroll
                for (int f = 0; f < 16; ++f) wf[f] = *(const bf16x8*)(wbase + f * 512);
                const unsigned short* A0 =
                    xbf + ((size_t)arow * S + s2) * H + sl * 256 + akoff;
#pragma unroll
                for (int ks = 0; ks < 8; ++ks) {
                    bf16x8 x0 = *(const bf16x8*)(A0 + ks * 32);
                    bf16x8 x1 = *(const bf16x8*)(A0 + (size_t)16 * S * H + ks * 32);
                    a00 = MFMA(x0, wf[ks*2+0], a00); a01 = MFMA(x0, wf[ks*2+1], a01);
                    a10 = MFMA(x1, wf[ks*2+0], a10); a11 = MFMA(x1, wf[ks*2+1], a11);
                }
            }
            const int slot = fs & 7;
#pragma unroll
            for (int r = 0; r < 4; ++r) {
                ring[slot][drow + r][dcol]           = f2bf(a00[r] + wb0);
                ring[slot][drow + r][16 + dcol]      = f2bf(a01[r] + wb1);
                ring[slot][16 + drow + r][dcol]      = f2bf(a10[r] + wb0);
                ring[slot][16 + drow + r][16 + dcol] = f2bf(a11[r] + wb1);
            }
            asm volatile("s_waitcnt lgkmcnt(0)" ::: "memory");
            if (lane == 0) *(volatile int*)&ring_ready[slot] = fs + 1;
        }
    }
}

// =====================================================================
// Host side
// =====================================================================
extern "C" void kernel_launch(void* const* d_in, const int* in_sizes, int n_in,
                              void* d_out, int out_size, void* d_ws, size_t ws_size,
                              hipStream_t stream)
{
    const float* x   = (const float*)d_in[0];
    const float* pad = (const float*)d_in[1];
    const float* Wfw = (const float*)d_in[2];
    const float* Ufw = (const float*)d_in[3];
    const float* bfw = (const float*)d_in[4];
    const float* Wbw = (const float*)d_in[5];
    const float* Ubw = (const float*)d_in[6];
    const float* bbw = (const float*)d_in[7];
    float* out = (float*)d_out;

    char* w = (char*)d_ws;
    unsigned short* wbufW = (unsigned short*)w;                     // 16.8 MB
    unsigned short* wbufU = wbufW + (size_t)1048576 * 8;            // 16.8 MB
    unsigned short* xbf   = wbufU + (size_t)1048576 * 8;            // 33.6 MB
    unsigned short* hhist = xbf + (size_t)B * S * H;                // 513 x 128 KB
    unsigned int*   flags = (unsigned int*)(hhist + (size_t)(S + 1) * HSLOT); // 1 KB
    unsigned int*   gen4  = flags + 256;                            // 128 uints

    // zero h slot 0, flags, gen4 (deterministic per call)
    hipMemsetAsync(hhist, 0, (size_t)HSLOT * sizeof(unsigned short), stream);
    hipMemsetAsync(flags, 0, (256 + 128) * sizeof(unsigned int), stream);

    prep_x<<<8192, 256, 0, stream>>>(x, xbf);
    prep_weights<<<4096, 256, 0, stream>>>(Wfw, Wbw, wbufW);
    prep_weights<<<4096, 256, 0, stream>>>(Ufw, Ubw, wbufU);

    void* args[] = { (void*)&wbufU, (void*)&wbufW, (void*)&xbf, (void*)&hhist,
                     (void*)&flags, (void*)&gen4, (void*)&pad,
                     (void*)&bfw, (void*)&bbw, (void*)&out };
    hipLaunchCooperativeKernel((void*)lstm_persist, dim3(NBLK), dim3(512),
                               args, 0, stream);
}

// Round 14
// 3120.113 us; speedup vs baseline: 1.5245x; 1.1509x over previous
//
#include <hip/hip_runtime.h>
#include <hip/hip_bf16.h>

#define B 32
#define S 512
#define H 1024
#define G 4096          // 4*H
#define NBLK 256
#define HSLOT 65536     // shorts per h slot (2 dirs x B x H)

typedef __attribute__((ext_vector_type(8))) short bf16x8;
typedef __attribute__((ext_vector_type(8))) unsigned short u16x8;
typedef __attribute__((ext_vector_type(4))) float f32x4;

__device__ __forceinline__ unsigned short f2bf(float v) {
    __hip_bfloat16 b = __float2bfloat16(v);
    return *reinterpret_cast<unsigned short*>(&b);
}
__device__ __forceinline__ float bf2f(unsigned short u) {
    union { float f; unsigned int i; } v; v.i = ((unsigned int)u) << 16; return v.f;
}
#define MFMA(a, b, c) __builtin_amdgcn_mfma_f32_16x16x32_bf16(a, b, c, 0, 0, 0)
#define ALOAD(p)    __hip_atomic_load((p),  __ATOMIC_RELAXED, __HIP_MEMORY_SCOPE_AGENT)
#define ASTORE(p,v) __hip_atomic_store((p), (v), __ATOMIC_RELAXED, __HIP_MEMORY_SCOPE_AGENT)

// =====================================================================
// prep_weights: fragment-ordered bf16 weights for one matrix pair (fw,bw).
// chunk idx = ((blk*4 + w)*16 + f)*64 + lane, 8 bf16/chunk; 1,048,576 chunks.
// =====================================================================
__global__ __launch_bounds__(256)
void prep_weights(const float* __restrict__ fw, const float* __restrict__ bw,
                  unsigned short* __restrict__ dst)
{
    size_t idx = (size_t)blockIdx.x * 256 + threadIdx.x;
    int lane = idx & 63;
    int f    = (idx >> 6) & 15;
    int w    = (idx >> 10) & 3;
    int blk  = (int)(idx >> 12);
    int dir  = blk >> 7, jg = blk & 127;
    int ks = f >> 1, ct = f & 1;

    int c  = ct * 16 + (lane & 15);
    int g  = (c >> 3) * H + jg * 8 + (c & 7);
    int kk = w * 256 + ks * 32 + ((lane >> 4) * 8);

    const float* src = dir ? bw : fw;
    u16x8 o;
#pragma unroll
    for (int i = 0; i < 8; ++i)
        o[i] = f2bf(src[(size_t)(kk + i) * G + g]);
    *(u16x8*)&dst[idx * 8] = o;
}

__global__ __launch_bounds__(256)
void prep_x(const float* __restrict__ x, unsigned short* __restrict__ xbf)
{
    size_t i8 = ((size_t)blockIdx.x * 256 + threadIdx.x) * 8;
    float4 v0 = *(const float4*)&x[i8];
    float4 v1 = *(const float4*)&x[i8 + 4];
    u16x8 o;
    o[0] = f2bf(v0.x); o[1] = f2bf(v0.y); o[2] = f2bf(v0.z); o[3] = f2bf(v0.w);
    o[4] = f2bf(v1.x); o[5] = f2bf(v1.y); o[6] = f2bf(v1.z); o[7] = f2bf(v1.w);
    *(u16x8*)&xbf[i8] = o;
}

// =====================================================================
// lstm_persist: one cooperative kernel, all 512 steps.
// 256 blocks x 512 threads. Block (dir,jg) owns 32 gate-cols.
// Barrier (mailbox fan-out, ONE LLC hop, single reader per line):
//  - producer block (dir,pjg): when all 4 gate waves' h stores are
//    vmcnt(0)-ack'd (LDS gcnt == 4(t+1)), gate wave w stores "t+1" into
//    mbox[dir][cjg][pjg] for cjg in [32w, 32w+32) — 32 scattered 4B
//    stores per wave, fire-and-forget.
//  - consumer U-wave w polls ITS OWN row segment mbox[dir][jg][32w..+32)
//    (128B contiguous, single reader) until all >= t. Quarter-granular:
//    wave w starts h-loads the moment its 32 producers are done.
// No master, no gen broadcast, no tok relay, NO setprio (spinning waves
// must not be boosted — R12/R13 lesson).
// Datapath (R9/R10-proven): h history buffer (fresh 128 KB slot per step,
// regular pipelined bf16x8 loads); U frags in LDS; W-waves free-run x@W
// into 8-slot LDS ring paced by gcnt. dout via nontemporal stores (keep
// LLC clean for W/x/h working set).
// =====================================================================
__global__ __launch_bounds__(512, 1)
void lstm_persist(const unsigned short* __restrict__ wbufU,
                  const unsigned short* __restrict__ wbufW,
                  const unsigned short* __restrict__ xbf,
                  unsigned short* __restrict__ hhist,  // 513 slots x HSLOT
                  unsigned int* __restrict__ mbox,     // [dir][cjg][pjg] 2x128x128
                  const float* __restrict__ pad,
                  const float* __restrict__ bfw, const float* __restrict__ bbw,
                  float* __restrict__ dout)
{
    const int blk = blockIdx.x;
    const int dir = blk >> 7;
    const int jg  = blk & 127;
    const int j0  = jg * 8;
    const int tid = threadIdx.x;
    const int wave = tid >> 6;
    const int lane = tid & 63;

    __shared__ short Uw[32768];                  // 64 KB U frags (wave-local regions)
    __shared__ float red[4][2][16][33];          // U partials
    __shared__ unsigned short ring[8][32][36];   // xz lookahead (bf16, bias folded)
    __shared__ unsigned rcnt;                    // red arrivals (monotone, 4/step)
    __shared__ unsigned gcnt;                    // gate publishes (monotone, 4/step)
    __shared__ int ring_ready[8];                // slot generation = fs+1

    if (tid == 0) { rcnt = 0; gcnt = 0; }
    if (tid < 8) ring_ready[tid] = 0;
    __syncthreads();   // the only block-wide barrier (init)

    const int arow  = lane & 15;
    const int akoff = (lane >> 4) * 8;
    const int drow  = (lane >> 4) * 4;
    const int dcol  = lane & 15;
    const float* bsrc = dir ? bbw : bfw;
    const float wb0 = bsrc[(dcol >> 3) * H + j0 + (dcol & 7)];
    const float wb1 = bsrc[(((16 + dcol) >> 3)) * H + j0 + ((16 + dcol) & 7)];

    if (wave < 4) {
        // ---- load this wave's U region into LDS (16 KB, wave-local) ----
        {
            const unsigned short* src = wbufU + (((size_t)blk * 4 + wave) * 16) * 512 + lane * 8;
#pragma unroll
            for (int f = 0; f < 16; ++f)
                *(u16x8*)&Uw[((wave * 16 + f) * 64 + lane) * 8] = *(const u16x8*)(src + f * 512);
        }

        float hst = 0.f, cst = 0.f;
        const int gb  = (tid >> 3) & 31;
        const int gj  = tid & 7;
        const int gbt = gb >> 4, grow = gb & 15;
        const f32x4 zero4 = {0.f, 0.f, 0.f, 0.f};
        // consumer: own mailbox row, this wave's quarter (single reader)
        const unsigned* mb_in = mbox + ((size_t)(dir * 128) + jg) * 128 + wave * 32;
        // producer: this wave fans out to consumers cjg in [32w, 32w+32)
        unsigned int* mb_out = mbox + ((size_t)(dir * 128) + wave * 32) * 128 + jg;

        for (int t = 0; t < S; ++t) {
            const int s = dir ? (S - 1 - t) : t;
            float pv = pad[gb * S + s];      // early issue, hidden under poll

            // ---- wait: this wave's 32 producers published step t-1 ----
            if (t) {
                bool ok;
                do {
                    unsigned v = ALOAD(&mb_in[lane & 31]);
                    ok = __all(v >= (unsigned)t);
                    if (!ok) __builtin_amdgcn_s_sleep(1);
                } while (!ok);
                asm volatile("" ::: "memory");
            }

            // ---- U phase: h(t-1) @ U, K-slice wave*256, pipelined loads ----
            f32x4 u00 = zero4, u01 = zero4, u10 = zero4, u11 = zero4;
            const unsigned short* hb = hhist + (size_t)t * HSLOT
                                     + ((size_t)(dir * B) + arow) * H + wave * 256 + akoff;
#pragma unroll
            for (int ks = 0; ks < 8; ++ks) {
                bf16x8 a0 = *(const bf16x8*)(hb + ks * 32);
                bf16x8 a1 = *(const bf16x8*)(hb + 16 * H + ks * 32);
                bf16x8 b0 = *(const bf16x8*)&Uw[((wave * 16 + ks * 2 + 0) * 64 + lane) * 8];
                bf16x8 b1 = *(const bf16x8*)&Uw[((wave * 16 + ks * 2 + 1) * 64 + lane) * 8];
                u00 = MFMA(a0, b0, u00); u01 = MFMA(a0, b1, u01);
                u10 = MFMA(a1, b0, u10); u11 = MFMA(a1, b1, u11);
            }
#pragma unroll
            for (int r = 0; r < 4; ++r) {
                red[wave][0][drow + r][dcol]      = u00[r];
                red[wave][0][drow + r][16 + dcol] = u01[r];
                red[wave][1][drow + r][dcol]      = u10[r];
                red[wave][1][drow + r][16 + dcol] = u11[r];
            }
            asm volatile("s_waitcnt lgkmcnt(0)" ::: "memory");
            if (lane == 0) atomicAdd(&rcnt, 1u);
            {
                const unsigned need = 4u * (unsigned)(t + 1);
                while (*(volatile unsigned*)&rcnt < need) {}
                asm volatile("" ::: "memory");
            }

            // ---- ring slot t (normally ready 4+ steps ago) ----
            while (*(volatile int*)&ring_ready[t & 7] < t + 1) {}
            asm volatile("" ::: "memory");

            // ---- gate ----
            float z[4];
#pragma unroll
            for (int q = 0; q < 4; ++q) {
                const int c = q * 8 + gj;
                float zz = bf2f(ring[t & 7][gb][c]);
#pragma unroll
                for (int w = 0; w < 4; ++w) zz += red[w][gbt][grow][c];
                z[q] = zz;
            }
            float ig = 1.f / (1.f + expf(-z[0]));
            float fg = 1.f / (1.f + expf(-z[1]));
            float gg = tanhf(z[2]);
            float og = 1.f / (1.f + expf(-z[3]));

            float m  = 1.f - pv;
            float cn = fg * cst + ig * gg;
            float hn = og * tanhf(cn);
            float h2 = fmaf(m, hn - hst, hst);
            float c2 = fmaf(m, cn - cst, cst);
            hst = h2; cst = c2;

            // ---- publish h(t) -> hhist[t+1] (8B packed agent stores) ----
            unsigned u = (unsigned)f2bf(h2);
            const int gl = lane & ~3;
            unsigned v0 = (unsigned)__shfl((int)u, gl + 0);
            unsigned v1 = (unsigned)__shfl((int)u, gl + 1);
            unsigned v2 = (unsigned)__shfl((int)u, gl + 2);
            unsigned v3 = (unsigned)__shfl((int)u, gl + 3);
            if ((lane & 3) == 0) {
                unsigned long long pk = (unsigned long long)(v0 & 0xffffu)
                                      | ((unsigned long long)(v1 & 0xffffu) << 16)
                                      | ((unsigned long long)(v2 & 0xffffu) << 32)
                                      | ((unsigned long long)(v3 & 0xffffu) << 48);
                unsigned long long* hp = (unsigned long long*)
                    (hhist + (size_t)(t + 1) * HSLOT
                           + ((size_t)(dir * B) + gb) * H + j0 + gj);
                ASTORE(hp, pk);
            }
            // per-wave ack of own h stores -> LDS gcnt
            asm volatile("s_waitcnt vmcnt(0)" ::: "memory");
            if (lane == 0) atomicAdd(&gcnt, 1u);
            // all 4 waves' h ack'd -> fan out this wave's 32 mailbox stores
            {
                const unsigned need = 4u * (unsigned)(t + 1);
                while (*(volatile unsigned*)&gcnt < need) {}
                asm volatile("" ::: "memory");
                if (lane < 32)
                    ASTORE(mb_out + (size_t)lane * 128, (unsigned)(t + 1));
            }

            // ---- dout (off the publication path, nontemporal) ----
            __builtin_nontemporal_store(h2,
                &dout[((size_t)gb * S + s) * (2 * H) + dir * H + j0 + gj]);
            if (t == S - 1) {
                size_t base = (size_t)B * S * 2 * H;
                __builtin_nontemporal_store(h2,
                    &dout[base + dir * 2 * B * H + gb * H + j0 + gj]);
                __builtin_nontemporal_store(c2,
                    &dout[base + dir * 2 * B * H + B * H + gb * H + j0 + gj]);
            }
        }
    } else {
        // ---- W waves: free-running xz producer, fs = wave-4, +4 ----
        const f32x4 zero4 = {0.f, 0.f, 0.f, 0.f};
        for (int fs = wave - 4; fs < S; fs += 4) {
            if (fs >= 8) {   // wait until gate consumed slot (step fs-8 done)
                const unsigned need = 4u * (unsigned)(fs - 7);
                while (*(volatile unsigned*)&gcnt < need)
                    __builtin_amdgcn_s_sleep(2);   // coarse: >=4-step slack
                asm volatile("" ::: "memory");
            }
            const int s2 = dir ? (S - 1 - fs) : fs;
            f32x4 a00 = zero4, a01 = zero4, a10 = zero4, a11 = zero4;
            for (int sl = 0; sl < 4; ++sl) {
                const unsigned short* wbase =
                    wbufW + (((size_t)blk * 4 + sl) * 16) * 512 + lane * 8;
                bf16x8 wf[16];
#pragma unroll
                for (int f = 0; f < 16; ++f) wf[f] = *(const bf16x8*)(wbase + f * 512);
                const unsigned short* A0 =
                    xbf + ((size_t)arow * S + s2) * H + sl * 256 + akoff;
#pragma unroll
                for (int ks = 0; ks < 8; ++ks) {
                    bf16x8 x0 = *(const bf16x8*)(A0 + ks * 32);
                    bf16x8 x1 = *(const bf16x8*)(A0 + (size_t)16 * S * H + ks * 32);
                    a00 = MFMA(x0, wf[ks*2+0], a00); a01 = MFMA(x0, wf[ks*2+1], a01);
                    a10 = MFMA(x1, wf[ks*2+0], a10); a11 = MFMA(x1, wf[ks*2+1], a11);
                }
            }
            const int slot = fs & 7;
#pragma unroll
            for (int r = 0; r < 4; ++r) {
                ring[slot][drow + r][dcol]           = f2bf(a00[r] + wb0);
                ring[slot][drow + r][16 + dcol]      = f2bf(a01[r] + wb1);
                ring[slot][16 + drow + r][dcol]      = f2bf(a10[r] + wb0);
                ring[slot][16 + drow + r][16 + dcol] = f2bf(a11[r] + wb1);
            }
            asm volatile("s_waitcnt lgkmcnt(0)" ::: "memory");
            if (lane == 0) *(volatile int*)&ring_ready[slot] = fs + 1;
        }
    }
}

// =====================================================================
// Host side
// =====================================================================
extern "C" void kernel_launch(void* const* d_in, const int* in_sizes, int n_in,
                              void* d_out, int out_size, void* d_ws, size_t ws_size,
                              hipStream_t stream)
{
    const float* x   = (const float*)d_in[0];
    const float* pad = (const float*)d_in[1];
    const float* Wfw = (const float*)d_in[2];
    const float* Ufw = (const float*)d_in[3];
    const float* bfw = (const float*)d_in[4];
    const float* Wbw = (const float*)d_in[5];
    const float* Ubw = (const float*)d_in[6];
    const float* bbw = (const float*)d_in[7];
    float* out = (float*)d_out;

    char* w = (char*)d_ws;
    unsigned short* wbufW = (unsigned short*)w;                     // 16.8 MB
    unsigned short* wbufU = wbufW + (size_t)1048576 * 8;            // 16.8 MB
    unsigned short* xbf   = wbufU + (size_t)1048576 * 8;            // 33.6 MB
    unsigned short* hhist = xbf + (size_t)B * S * H;                // 513 x 128 KB
    unsigned int*   mbox  = (unsigned int*)(hhist + (size_t)(S + 1) * HSLOT); // 128 KB

    // zero h slot 0 + mailbox (deterministic per call)
    hipMemsetAsync(hhist, 0, (size_t)HSLOT * sizeof(unsigned short), stream);
    hipMemsetAsync(mbox, 0, (size_t)2 * 128 * 128 * sizeof(unsigned int), stream);

    prep_x<<<8192, 256, 0, stream>>>(x, xbf);
    prep_weights<<<4096, 256, 0, stream>>>(Wfw, Wbw, wbufW);
    prep_weights<<<4096, 256, 0, stream>>>(Ufw, Ubw, wbufU);

    void* args[] = { (void*)&wbufU, (void*)&wbufW, (void*)&xbf, (void*)&hhist,
                     (void*)&mbox, (void*)&pad,
                     (void*)&bfw, (void*)&bbw, (void*)&out };
    hipLaunchCooperativeKernel((void*)lstm_persist, dim3(NBLK), dim3(512),
                               args, 0, stream);
}